// Round 8
// baseline (387.220 us; speedup 1.0000x reference)
//
#include <hip/hip_runtime.h>

#define NK 512
#define ND 64
#define NHW 4096
#define NPIX 131072            // 32*64*64
#define OUT_ELEMS 8388608      // 32*64*64*64
#define PT 16                  // pixels per wave
#define XS 68                  // LDS x-row stride in floats

// ---------------------------------------------------------------------------
// Prep: sc[k] = numpy-pairwise-8 fp32 sum of fl(c_d^2); zero the two loss
// slots (harness re-poisons d_out/d_ws to 0xAA before every timed replay).
// ---------------------------------------------------------------------------
__global__ __launch_bounds__(256) void vq_prep(const float* __restrict__ cb,
                                               float* __restrict__ sc,
                                               float* __restrict__ losses) {
#pragma clang fp contract(off)
  {
    int k = blockIdx.x * 256 + threadIdx.x;   // grid 2*256 = 512
    const float* c = cb + (size_t)k * ND;
    float q[ND];
#pragma unroll
    for (int d = 0; d < ND; ++d) q[d] = c[d] * c[d];
    float r[8];
#pragma unroll
    for (int j = 0; j < 8; ++j) r[j] = q[j];
#pragma unroll
    for (int i = 8; i < ND; i += 8)
#pragma unroll
      for (int j = 0; j < 8; ++j) r[j] += q[i + j];
    float res = ((r[0] + r[1]) + (r[2] + r[3])) + ((r[4] + r[5]) + (r[6] + r[7]));
    sc[k] = res;
    if (k < 2) losses[k] = 0.f;
  }
}

// ---------------------------------------------------------------------------
// Main: ONE WAVE per block, lane = code. Wave holds a 128-code tile in 128
// VGPRs (tiles reloaded 4x from L2-resident cb) and sweeps 16 pixels; per
// (pixel,dq): 1 broadcast ds_read_b128 of x feeds 8 FMAs (vs R7's 9 LDS ops
// per 8 FMA-quads -> LDS pipe saturated at 203 us). K-loop: zero SMEM (R5's
// OOO-drain), zero per-element VMEM (R6), minimal LDS. Running per-lane
// argmin across the 4 passes lives in LDS (ascending pass order, strict '<');
// final 64-lane shuffle reduce with (val,idx) lexicographic compare.
// Numerics bit-identical to the passing R2/R5/R7 kernels:
//   d2[n,k] = fl(fl(Sx_n - fl(2*M)) + Sc_k), M = sequential fp32 FMA chain
//   d=0..63, Sx numpy pairwise-8; lowest index wins ties = np.argmin.
// ---------------------------------------------------------------------------
__global__ __launch_bounds__(64)
__attribute__((amdgpu_waves_per_eu(3, 3)))
void vq_main(const float* __restrict__ x,
             const float* __restrict__ cb,
             const float* __restrict__ sc,
             float* __restrict__ out,
             float* __restrict__ idx_out,
             float* __restrict__ losses) {
#pragma clang fp contract(off)
  {
    __shared__ float lx[PT * XS];          // 4.3 KB x tile [pixel][d]
    __shared__ float sxb[PT];              // per-pixel Sx
    __shared__ float mval[PT][64];         // running min per (pixel, lane)
    __shared__ int   midx[PT][64];
    __shared__ int   shw[PT];

    const int l = threadIdx.x;             // 0..63 (lane = code-in-tile)
    const int p16 = l & 15, dg = l >> 4;
    const int g0 = blockIdx.x * PT;
    const int b = g0 >> 12;
    const int hw0 = g0 & 4095;
    const float* xbase = x + (size_t)b * (ND * NHW) + hw0;

    // ---- Stage x tile (lane -> pixel p16, dims dg*16..dg*16+15; coalesced
    // 64B segments) and init the running-min buffers.
#pragma unroll
    for (int j = 0; j < 16; ++j) {
      const int d = dg * 16 + j;
      lx[p16 * XS + d] = xbase[(size_t)d * NHW + p16];
    }
#pragma unroll
    for (int n = 0; n < PT; ++n) { mval[n][l] = 3.0e38f; midx[n][l] = 0; }
    __syncthreads();

    // ---- Sx per pixel (lanes 0..15): rounded squares, pairwise-8 (= R2).
    if (l < PT) {
      float r[8];
      float4 q0 = *(const float4*)&lx[l * XS + 0];
      float4 q1 = *(const float4*)&lx[l * XS + 4];
      r[0] = q0.x * q0.x; r[1] = q0.y * q0.y; r[2] = q0.z * q0.z; r[3] = q0.w * q0.w;
      r[4] = q1.x * q1.x; r[5] = q1.y * q1.y; r[6] = q1.z * q1.z; r[7] = q1.w * q1.w;
#pragma unroll
      for (int i = 2; i < 16; i += 2) {
        float4 a = *(const float4*)&lx[l * XS + i * 4];
        float4 c = *(const float4*)&lx[l * XS + i * 4 + 4];
        r[0] += a.x * a.x; r[1] += a.y * a.y; r[2] += a.z * a.z; r[3] += a.w * a.w;
        r[4] += c.x * c.x; r[5] += c.y * c.y; r[6] += c.z * c.z; r[7] += c.w * c.w;
      }
      sxb[l] = ((r[0] + r[1]) + (r[2] + r[3])) + ((r[4] + r[5]) + (r[6] + r[7]));
    }
    __syncthreads();

    // ---- 4 passes of 128 codes; c-tile resident in 128 VGPRs.
    for (int pass = 0; pass < 4; ++pass) {
      const int k0 = pass * 128;
      const float4* r0 = (const float4*)(cb + (size_t)(k0 + l) * ND);
      const float4* r1 = (const float4*)(cb + (size_t)(k0 + 64 + l) * ND);
      float4 c0q[16], c1q[16];
#pragma unroll
      for (int dq = 0; dq < 16; ++dq) c0q[dq] = r0[dq];
#pragma unroll
      for (int dq = 0; dq < 16; ++dq) c1q[dq] = r1[dq];
      const float s0 = sc[k0 + l];
      const float s1 = sc[k0 + 64 + l];

      for (int n = 0; n < PT; ++n) {
        const float* xrow = &lx[n * XS];
        float a0 = 0.f, a1 = 0.f;
#pragma unroll
        for (int dq = 0; dq < 16; ++dq) {
          const float4 xq = *(const float4*)&xrow[dq * 4];   // broadcast b128
          a0 = __builtin_fmaf(c0q[dq].x, xq.x, a0);          // sequential
          a0 = __builtin_fmaf(c0q[dq].y, xq.y, a0);          // chain d=0..63
          a0 = __builtin_fmaf(c0q[dq].z, xq.z, a0);
          a0 = __builtin_fmaf(c0q[dq].w, xq.w, a0);
          a1 = __builtin_fmaf(c1q[dq].x, xq.x, a1);
          a1 = __builtin_fmaf(c1q[dq].y, xq.y, a1);
          a1 = __builtin_fmaf(c1q[dq].z, xq.z, a1);
          a1 = __builtin_fmaf(c1q[dq].w, xq.w, a1);
        }
        const float Sxn = sxb[n];                            // broadcast b32
        const float d20 = (Sxn - 2.0f * a0) + s0;
        const float d21 = (Sxn - 2.0f * a1) + s1;
        float m2 = d20; int i2 = k0 + l;                     // tile0 code
        if (d21 < m2) { m2 = d21; i2 = k0 + 64 + l; }        // strict '<'
        if (m2 < mval[n][l]) { mval[n][l] = m2; midx[n][l] = i2; }
      }
    }
    __syncthreads();

    // ---- Per-pixel exact argmin across 64 lanes: lexicographic (val, idx).
    for (int n = 0; n < PT; ++n) {
      float m = mval[n][l];
      int i = midx[n][l];
#pragma unroll
      for (int s = 1; s < 64; s <<= 1) {
        const float om = __shfl_xor(m, s, 64);
        const int oi = __shfl_xor(i, s, 64);
        if (om < m || (om == m && oi < i)) { m = om; i = oi; }
      }
      if (l == 0) shw[n] = i;
    }
    __syncthreads();
    if (l < PT) idx_out[g0 + l] = (float)shw[l];             // coalesced

    // ---- Epilogue: gather winning codes (L2), write transposed, loss.
    const int widx = shw[p16];
    const float* qrow = cb + (size_t)widx * ND;
    float* op = out + (size_t)b * (ND * NHW) + hw0;
    float lossp = 0.f;
#pragma unroll
    for (int j = 0; j < 16; ++j) {
      const int d = dg * 16 + j;
      const float qv = qrow[d];
      const float xv = lx[p16 * XS + d];
      const float e = xv - qv;
      lossp = __builtin_fmaf(e, e, lossp);
      op[(size_t)d * NHW + p16] = qv;
    }
#pragma unroll
    for (int off = 32; off; off >>= 1) lossp += __shfl_down(lossp, off);
    if (l == 0) {
      const float t = lossp * (1.f / 8388608.f);
      atomicAdd(losses + 0, t);   // dictionary_loss
      atomicAdd(losses + 1, t);   // commitment_loss (identical forward value)
    }
  }
}

extern "C" void kernel_launch(void* const* d_in, const int* in_sizes, int n_in,
                              void* d_out, int out_size, void* d_ws, size_t ws_size,
                              hipStream_t stream) {
  const float* x  = (const float*)d_in[0];   // [32,64,64,64] fp32
  const float* cb = (const float*)d_in[1];   // [512,64] fp32
  float* out     = (float*)d_out;            // quantized [B,D,H,W]
  float* idx_out = out + OUT_ELEMS;          // indices (as fp32) [B,H,W]
  float* losses  = idx_out + NPIX;           // 2 scalars
  float* sc      = (float*)d_ws;             // 512 floats scratch

  vq_prep<<<2, 256, 0, stream>>>(cb, sc, losses);
  vq_main<<<NPIX / PT, 64, 0, stream>>>(x, cb, sc, out, idx_out, losses);
}

// Round 10
// 228.455 us; speedup vs baseline: 1.6950x; 1.6950x over previous
//
#include <hip/hip_runtime.h>

#define NK 512
#define ND 64
#define NHW 4096
#define NPIX 131072            // 32*64*64
#define OUT_ELEMS 8388608      // 32*64*64*64
#define XS 68                  // LDS x-row stride (floats)
#define CS 68                  // LDS chunk-row stride (floats)

// ---------------------------------------------------------------------------
// Prep: sc[k] = numpy-pairwise-8 fp32 sum of fl(c_d^2); zero the two loss
// slots (harness re-poisons d_out/d_ws to 0xAA before every timed replay).
// ---------------------------------------------------------------------------
__global__ __launch_bounds__(256) void vq_prep(const float* __restrict__ cb,
                                               float* __restrict__ sc,
                                               float* __restrict__ losses) {
#pragma clang fp contract(off)
  {
    int k = blockIdx.x * 256 + threadIdx.x;   // grid 2*256 = 512
    const float* c = cb + (size_t)k * ND;
    float q[ND];
#pragma unroll
    for (int d = 0; d < ND; ++d) q[d] = c[d] * c[d];
    float r[8];
#pragma unroll
    for (int j = 0; j < 8; ++j) r[j] = q[j];
#pragma unroll
    for (int i = 8; i < ND; i += 8)
#pragma unroll
      for (int j = 0; j < 8; ++j) r[j] += q[i + j];
    float res = ((r[0] + r[1]) + (r[2] + r[3])) + ((r[4] + r[5]) + (r[6] + r[7]));
    sc[k] = res;
    if (k < 2) losses[k] = 0.f;
  }
}

// ---------------------------------------------------------------------------
// Main: 64 pixels/block, 256 threads, 2-D register tiling. Wave wv owns
// pixels {wv*16 + i*4 + r}; lane (r=lane&3, c=lane>>2) computes those 4
// pixels x 4 codes {j*16+c} of the 64-code LDS chunk. Per dq-step: 8
// ds_read_b128 feed 64 FMAs (R7: 18 reads for same FMAs -> LDS-bound).
// R9's bug: GEMM read pixels (i*4+r) without the wv*16 offset — all waves
// computed pixels 0..15 and pixels 16..63 got copied argmins. Fixed here
// (x/Sx reads now use wv*16 + i*4 + r, matching the px write side).
// Numerics bit-identical to passing R2/R5/R7: per-(n,k) sequential fp32 FMA
// chain d=0..63; d2 = fl(fl(Sx - fl(2M)) + Sc); Sx numpy pairwise-8; within-
// lane candidates ascend in code + strict '<'; cross-lane lexicographic
// (val,idx) min => lowest index wins ties = np.argmin.
// ---------------------------------------------------------------------------
__global__ __launch_bounds__(256, 2) void vq_main(const float* __restrict__ x,
                                                  const float* __restrict__ cb,
                                                  const float* __restrict__ sc,
                                                  float* __restrict__ out,
                                                  float* __restrict__ idx_out,
                                                  float* __restrict__ losses) {
#pragma clang fp contract(off)
  {
    __shared__ float lx[64 * XS];     // 17.4 KB x tile [pixel][d]
    __shared__ float lcb[64 * CS];    // 17.4 KB 64-code chunk [code][d]
    __shared__ float lsc[NK];         // 2 KB
    __shared__ float sxb[64];         // per-pixel Sx
    __shared__ int   shw[64];         // winning code per pixel
    __shared__ float red[4];

    const int tid = threadIdx.x;
    const int wv = __builtin_amdgcn_readfirstlane(tid >> 6);  // wave id
    const int lane = tid & 63;
    const int r = lane & 3;           // pixel row (within wave's 16)
    const int c = lane >> 2;          // code col
    const int g0 = blockIdx.x * 64;
    const int b = g0 >> 12;
    const int hw0 = g0 & 4095;
    const float* xbase = x + (size_t)b * (ND * NHW) + hw0;

    // ---- Stage x tile: thread (p=lane, wv) loads dims (coalesced).
    const int p = lane;
#pragma unroll
    for (int i = 0; i < 4; ++i) {
      const int d = (wv + i * 4) * 4;
      float4 q;
      q.x = xbase[(size_t)(d + 0) * NHW + p];
      q.y = xbase[(size_t)(d + 1) * NHW + p];
      q.z = xbase[(size_t)(d + 2) * NHW + p];
      q.w = xbase[(size_t)(d + 3) * NHW + p];
      *(float4*)&lx[p * XS + d] = q;
    }
    // sc -> LDS (2 floats/thread).
    *(float2*)&lsc[tid * 2] = ((const float2*)sc)[tid];

    // ---- Prefetch chunk 0 to regs: thread t holds code kk=t>>2, quads
    // (t&3)+{0,4,8,12} (coalesced 16-B granules).
    const int kk = tid >> 2, qq = tid & 3;
    float4 pf0, pf1, pf2, pf3;
    {
      const float4* src = (const float4*)(cb) + kk * 16;
      pf0 = src[qq];  pf1 = src[qq + 4];  pf2 = src[qq + 8];  pf3 = src[qq + 12];
    }

    float m1[4] = {3.0e38f, 3.0e38f, 3.0e38f, 3.0e38f};
    int   i1[4] = {0, 0, 0, 0};

    for (int g = 0; g < 8; ++g) {
      __syncthreads();                       // prev chunk fully consumed
      {                                      // regs -> LDS chunk buffer
        float* dst = &lcb[kk * CS];
        *(float4*)&dst[(qq + 0) * 4]  = pf0;
        *(float4*)&dst[(qq + 4) * 4]  = pf1;
        *(float4*)&dst[(qq + 8) * 4]  = pf2;
        *(float4*)&dst[(qq + 12) * 4] = pf3;
      }
      if (g == 0 && wv == 0) {
        // Sx for pixel `lane`: rounded squares, pairwise-8 (bitwise = R2).
        float rr[8];
        float4 q0 = *(const float4*)&lx[lane * XS + 0];
        float4 q1 = *(const float4*)&lx[lane * XS + 4];
        rr[0] = q0.x * q0.x; rr[1] = q0.y * q0.y; rr[2] = q0.z * q0.z; rr[3] = q0.w * q0.w;
        rr[4] = q1.x * q1.x; rr[5] = q1.y * q1.y; rr[6] = q1.z * q1.z; rr[7] = q1.w * q1.w;
#pragma unroll
        for (int i = 2; i < 16; i += 2) {
          float4 a = *(const float4*)&lx[lane * XS + i * 4];
          float4 e = *(const float4*)&lx[lane * XS + i * 4 + 4];
          rr[0] += a.x * a.x; rr[1] += a.y * a.y; rr[2] += a.z * a.z; rr[3] += a.w * a.w;
          rr[4] += e.x * e.x; rr[5] += e.y * e.y; rr[6] += e.z * e.z; rr[7] += e.w * e.w;
        }
        sxb[lane] = ((rr[0] + rr[1]) + (rr[2] + rr[3])) + ((rr[4] + rr[5]) + (rr[6] + rr[7]));
      }
      __syncthreads();                       // chunk (and Sx) visible
      if (g < 7) {                           // prefetch next chunk
        const float4* src = (const float4*)(cb + (size_t)(g + 1) * 64 * ND) + kk * 16;
        pf0 = src[qq];  pf1 = src[qq + 4];  pf2 = src[qq + 8];  pf3 = src[qq + 12];
      }

      // ---- Register-tiled GEMM: this wave's 4 pixel-rows x 4 code-cols.
      const int px0 = wv * 16 + r;           // pixels px0 + {0,4,8,12}
      float a00 = 0.f, a01 = 0.f, a02 = 0.f, a03 = 0.f;   // a[j][i]
      float a10 = 0.f, a11 = 0.f, a12 = 0.f, a13 = 0.f;
      float a20 = 0.f, a21 = 0.f, a22 = 0.f, a23 = 0.f;
      float a30 = 0.f, a31 = 0.f, a32 = 0.f, a33 = 0.f;
#pragma unroll
      for (int dq = 0; dq < 16; ++dq) {
        float4 xq0 = *(const float4*)&lx[(px0 + 0)  * XS + dq * 4];
        float4 xq1 = *(const float4*)&lx[(px0 + 4)  * XS + dq * 4];
        float4 xq2 = *(const float4*)&lx[(px0 + 8)  * XS + dq * 4];
        float4 xq3 = *(const float4*)&lx[(px0 + 12) * XS + dq * 4];
        float4 cq0 = *(const float4*)&lcb[(0 * 16 + c) * CS + dq * 4];
        float4 cq1 = *(const float4*)&lcb[(1 * 16 + c) * CS + dq * 4];
        float4 cq2 = *(const float4*)&lcb[(2 * 16 + c) * CS + dq * 4];
        float4 cq3 = *(const float4*)&lcb[(3 * 16 + c) * CS + dq * 4];
#define VQ_FMA4(AJ, CQ, XQ)                                   \
        AJ = __builtin_fmaf(CQ.x, XQ.x, AJ);                  \
        AJ = __builtin_fmaf(CQ.y, XQ.y, AJ);                  \
        AJ = __builtin_fmaf(CQ.z, XQ.z, AJ);                  \
        AJ = __builtin_fmaf(CQ.w, XQ.w, AJ);
        VQ_FMA4(a00, cq0, xq0) VQ_FMA4(a01, cq0, xq1) VQ_FMA4(a02, cq0, xq2) VQ_FMA4(a03, cq0, xq3)
        VQ_FMA4(a10, cq1, xq0) VQ_FMA4(a11, cq1, xq1) VQ_FMA4(a12, cq1, xq2) VQ_FMA4(a13, cq1, xq3)
        VQ_FMA4(a20, cq2, xq0) VQ_FMA4(a21, cq2, xq1) VQ_FMA4(a22, cq2, xq2) VQ_FMA4(a23, cq2, xq3)
        VQ_FMA4(a30, cq3, xq0) VQ_FMA4(a31, cq3, xq1) VQ_FMA4(a32, cq3, xq2) VQ_FMA4(a33, cq3, xq3)
#undef VQ_FMA4
      }

      // ---- Combine + running argmin (codes ascend: j then later chunks).
      const int kb = g * 64;
      const float s0 = lsc[kb + 0 * 16 + c];
      const float s1 = lsc[kb + 1 * 16 + c];
      const float s2 = lsc[kb + 2 * 16 + c];
      const float s3 = lsc[kb + 3 * 16 + c];
      const float Sx0 = sxb[px0 + 0];
      const float Sx1 = sxb[px0 + 4];
      const float Sx2 = sxb[px0 + 8];
      const float Sx3 = sxb[px0 + 12];
#define VQ_UPD(J, SJ, AI0, AI1, AI2, AI3)                                   \
      {                                                                     \
        const int code = kb + J * 16 + c;                                   \
        float d2;                                                           \
        d2 = (Sx0 - 2.0f * AI0) + SJ; if (d2 < m1[0]) { m1[0] = d2; i1[0] = code; } \
        d2 = (Sx1 - 2.0f * AI1) + SJ; if (d2 < m1[1]) { m1[1] = d2; i1[1] = code; } \
        d2 = (Sx2 - 2.0f * AI2) + SJ; if (d2 < m1[2]) { m1[2] = d2; i1[2] = code; } \
        d2 = (Sx3 - 2.0f * AI3) + SJ; if (d2 < m1[3]) { m1[3] = d2; i1[3] = code; } \
      }
      VQ_UPD(0, s0, a00, a01, a02, a03)
      VQ_UPD(1, s1, a10, a11, a12, a13)
      VQ_UPD(2, s2, a20, a21, a22, a23)
      VQ_UPD(3, s3, a30, a31, a32, a33)
#undef VQ_UPD
    }

    // ---- Cross-lane argmin per pixel: reduce over the 16 cols (lane bits
    // 2..5); lexicographic (val, idx) => exact np.argmin tie-breaking.
#pragma unroll
    for (int i = 0; i < 4; ++i) {
      float m = m1[i];
      int ii = i1[i];
#pragma unroll
      for (int s = 4; s < 64; s <<= 1) {
        const float om = __shfl_xor(m, s, 64);
        const int oi = __shfl_xor(ii, s, 64);
        if (om < m || (om == m && oi < ii)) { m = om; ii = oi; }
      }
      if (c == 0) {
        const int px = wv * 16 + i * 4 + r;   // same pixel the GEMM computed
        shw[px] = ii;
        idx_out[g0 + px] = (float)ii;
      }
    }
    __syncthreads();

    // ---- Epilogue: wave wv writes dims [wv*16,+16) for all 64 pixels.
    const int widx = shw[p];
    const float* qrow = cb + (size_t)widx * ND;
    float* op = out + (size_t)b * (ND * NHW) + hw0;
    float lossp = 0.f;
#pragma unroll
    for (int j = 0; j < 4; ++j) {
      const int d = wv * 16 + j * 4;
      const float4 q = *(const float4*)(qrow + d);
      const float4 xq = *(const float4*)&lx[p * XS + d];
      float e;
      e = xq.x - q.x; lossp = __builtin_fmaf(e, e, lossp); op[(size_t)(d + 0) * NHW + p] = q.x;
      e = xq.y - q.y; lossp = __builtin_fmaf(e, e, lossp); op[(size_t)(d + 1) * NHW + p] = q.y;
      e = xq.z - q.z; lossp = __builtin_fmaf(e, e, lossp); op[(size_t)(d + 2) * NHW + p] = q.z;
      e = xq.w - q.w; lossp = __builtin_fmaf(e, e, lossp); op[(size_t)(d + 3) * NHW + p] = q.w;
    }
#pragma unroll
    for (int off = 32; off; off >>= 1) lossp += __shfl_down(lossp, off);
    if (lane == 0) red[wv] = lossp;
    __syncthreads();
    if (tid == 0) {
      float t = (red[0] + red[1] + red[2] + red[3]) * (1.f / 8388608.f);
      atomicAdd(losses + 0, t);   // dictionary_loss
      atomicAdd(losses + 1, t);   // commitment_loss (identical forward value)
    }
  }
}

extern "C" void kernel_launch(void* const* d_in, const int* in_sizes, int n_in,
                              void* d_out, int out_size, void* d_ws, size_t ws_size,
                              hipStream_t stream) {
  const float* x  = (const float*)d_in[0];   // [32,64,64,64] fp32
  const float* cb = (const float*)d_in[1];   // [512,64] fp32
  float* out     = (float*)d_out;            // quantized [B,D,H,W]
  float* idx_out = out + OUT_ELEMS;          // indices (as fp32) [B,H,W]
  float* losses  = idx_out + NPIX;           // 2 scalars
  float* sc      = (float*)d_ws;             // 512 floats scratch

  vq_prep<<<2, 256, 0, stream>>>(cb, sc, losses);
  vq_main<<<NPIX / 64, 256, 0, stream>>>(x, cb, sc, out, idx_out, losses);
}